// Round 2
// baseline (2188.388 us; speedup 1.0000x reference)
//
#include <hip/hip_runtime.h>
#include <math.h>

// DPCA2D: dual-pruned cosine-sim cross-attention.
// Dims (fixed): B=8, C=256, Nq=9216 (96x96), Nc=4096 (64x64),
// INNER=512, HEADS=8, D=64, BH=64, top-k 8x8 -> 64 kept tokens.
//
// Workspace budget: SlotA (75.5 MB, aliased qs_n -> k -> out_pre) +
// SlotB (151 MB, q / attention in-place) + ~7.6 MB scratch = 223 MiB.
// ctx_n is staged in d_out (written last by final_kernel).

#define EPSN 1e-5f

// ---------------- channel LayerNorm (over 256 channels) ----------------
__global__ __launch_bounds__(256) void chan_norm_kernel(
    const float* __restrict__ x, const float* __restrict__ g,
    const float* __restrict__ bb, float* __restrict__ y, int N)
{
    int idx = blockIdx.x * 256 + threadIdx.x;
    int b = idx / N, p = idx - b * N;
    const float* xb = x + (size_t)b * 256 * N + p;
    float mean = 0.f, m2 = 0.f;
    for (int c = 0; c < 256; ++c) {
        float v = xb[(size_t)c * N];
        mean += v; m2 += v * v;
    }
    mean *= (1.f / 256.f); m2 *= (1.f / 256.f);
    float inv = 1.f / sqrtf(m2 - mean * mean + EPSN);
    float* yb = y + (size_t)b * 256 * N + p;
    for (int c = 0; c < 256; ++c) {
        yb[(size_t)c * N] = (xb[(size_t)c * N] - mean) * inv * g[c] + bb[c];
    }
}

// ---------------- fp32 tiled GEMM: C[z] = A (MxK) * B[z] (KxN) ----------
// 64x64 tile per block, 256 threads, 4x4 per thread, BK=16.
__global__ __launch_bounds__(256) void gemm_fp32(
    const float* __restrict__ A, const float* __restrict__ B,
    float* __restrict__ C, int M, int N, int K,
    long long strideB, long long strideC)
{
    const float* Bb = B + (size_t)blockIdx.z * strideB;
    float* Cb = C + (size_t)blockIdx.z * strideC;
    int n0 = blockIdx.x * 64;
    int m0 = blockIdx.y * 64;
    __shared__ float As[16][64];   // As[k][m]
    __shared__ float Bs[16][64];   // Bs[k][n]
    int t = threadIdx.x;
    int tm = (t >> 4) << 2;
    int tn = (t & 15) << 2;
    int ar = t >> 2;          // A tile row 0..63
    int ak = (t & 3) << 2;    // A tile k-col 0,4,8,12
    int bkr = t >> 4;         // B tile k-row 0..15
    int bnc = (t & 15) << 2;  // B tile n-col
    float acc[4][4] = {};
    for (int k0 = 0; k0 < K; k0 += 16) {
        float4 av = *(const float4*)(A + (size_t)(m0 + ar) * K + k0 + ak);
        float4 bv = *(const float4*)(Bb + (size_t)(k0 + bkr) * N + n0 + bnc);
        __syncthreads();
        As[ak + 0][ar] = av.x; As[ak + 1][ar] = av.y;
        As[ak + 2][ar] = av.z; As[ak + 3][ar] = av.w;
        *(float4*)(&Bs[bkr][bnc]) = bv;
        __syncthreads();
        #pragma unroll
        for (int kk = 0; kk < 16; ++kk) {
            float a0 = As[kk][tm + 0], a1 = As[kk][tm + 1];
            float a2 = As[kk][tm + 2], a3 = As[kk][tm + 3];
            float4 b4 = *(const float4*)(&Bs[kk][tn]);
            acc[0][0] += a0 * b4.x; acc[0][1] += a0 * b4.y; acc[0][2] += a0 * b4.z; acc[0][3] += a0 * b4.w;
            acc[1][0] += a1 * b4.x; acc[1][1] += a1 * b4.y; acc[1][2] += a1 * b4.z; acc[1][3] += a1 * b4.w;
            acc[2][0] += a2 * b4.x; acc[2][1] += a2 * b4.y; acc[2][2] += a2 * b4.z; acc[2][3] += a2 * b4.w;
            acc[3][0] += a3 * b4.x; acc[3][1] += a3 * b4.y; acc[3][2] += a3 * b4.z; acc[3][3] += a3 * b4.w;
        }
    }
    #pragma unroll
    for (int i = 0; i < 4; ++i) {
        float4 st = make_float4(acc[i][0], acc[i][1], acc[i][2], acc[i][3]);
        *(float4*)(Cb + (size_t)(m0 + tm + i) * N + n0 + tn) = st;
    }
}

// ---------------- l2 inverse norm per (bh, p) over 64 channels ----------
__global__ __launch_bounds__(256) void l2inv_kernel(
    const float* __restrict__ x, float* __restrict__ inv, int N,
    long long strideB, long long strideH)
{
    int idx = blockIdx.x * 256 + threadIdx.x;  // bh*N + p
    int bh = idx / N, p = idx - bh * N;
    const float* base = x + (size_t)(bh >> 3) * strideB + (size_t)(bh & 7) * strideH + p;
    float ss = 0.f;
    #pragma unroll 8
    for (int d = 0; d < 64; ++d) { float v = base[(size_t)d * N]; ss += v * v; }
    inv[idx] = 1.f / fmaxf(sqrtf(ss), 1e-12f);
}

// ---------------- row/col sums of |k_normalized| per bh ------------------
// k layout: (b, 512, 4096). krow[bh][d][h], kcol[bh][d][w].
__global__ __launch_bounds__(256) void krowcol_kernel(
    const float* __restrict__ k, const float* __restrict__ invnk,
    float* __restrict__ krow, float* __restrict__ kcol)
{
    int bh = blockIdx.x, b = bh >> 3, h = bh & 7;
    const float* kbase = k + ((size_t)b * 512 + (size_t)h * 64) * 4096;
    __shared__ float inv_s[4096];
    __shared__ float tile[64 * 65];
    int t = threadIdx.x;
    for (int l = t; l < 4096; l += 256) inv_s[l] = invnk[(size_t)bh * 4096 + l];
    for (int d = 0; d < 64; ++d) {
        __syncthreads();
        for (int l = t; l < 4096; l += 256)
            tile[(l >> 6) * 65 + (l & 63)] = kbase[(size_t)d * 4096 + l];
        __syncthreads();
        if (t < 64) {
            float s = 0.f;
            for (int w = 0; w < 64; ++w) s += fabsf(tile[t * 65 + w]) * inv_s[t * 64 + w];
            krow[((size_t)bh * 64 + d) * 64 + t] = s;
        } else if (t < 128) {
            int w = t - 64;
            float s = 0.f;
            for (int hh = 0; hh < 64; ++hh) s += fabsf(tile[hh * 65 + w]) * inv_s[hh * 64 + w];
            kcol[((size_t)bh * 64 + d) * 64 + w] = s;
        }
    }
}

// ---------------- q_probe[bh][d] = sum_p q_n[bh,d,p] ---------------------
__global__ __launch_bounds__(256) void qprobe_kernel(
    const float* __restrict__ q, const float* __restrict__ invnq,
    float* __restrict__ qprobe)
{
    int bh = blockIdx.x >> 6;
    int d = blockIdx.x & 63;
    const float* base = q + ((size_t)bh * 64 + d) * 9216;
    const float* ib = invnq + (size_t)bh * 9216;
    float s = 0.f;
    for (int p = threadIdx.x; p < 9216; p += 256) s += base[p] * ib[p];
    __shared__ float red[256];
    red[threadIdx.x] = s;
    __syncthreads();
    for (int off = 128; off > 0; off >>= 1) {
        if (threadIdx.x < off) red[threadIdx.x] += red[threadIdx.x + off];
        __syncthreads();
    }
    if (threadIdx.x == 0) qprobe[blockIdx.x] = red[0];
}

// ---------------- top-8 row/col selection per bh -------------------------
__global__ void topk_kernel(const float* __restrict__ qprobe,
                            const float* __restrict__ krow,
                            const float* __restrict__ kcol,
                            int* __restrict__ toph, int* __restrict__ topw)
{
    int bh = blockIdx.x, t = threadIdx.x;  // 64 threads
    __shared__ float qp[64], sr[64], sc[64];
    qp[t] = qprobe[bh * 64 + t];
    __syncthreads();
    float s1 = 0.f, s2 = 0.f;
    for (int d = 0; d < 64; ++d) {
        float qv = qp[d];
        s1 += qv * krow[((size_t)bh * 64 + d) * 64 + t];
        s2 += qv * kcol[((size_t)bh * 64 + d) * 64 + t];
    }
    sr[t] = s1; sc[t] = s2;
    __syncthreads();
    if (t == 0) {
        unsigned long long used = 0ull;
        for (int it = 0; it < 8; ++it) {
            int best = -1; float bv = -INFINITY;
            for (int i = 0; i < 64; ++i)
                if (!((used >> i) & 1ull) && sr[i] > bv) { bv = sr[i]; best = i; }
            if (best < 0) best = it;  // NaN guard: never emit a bad index
            used |= 1ull << best;
            toph[bh * 8 + it] = best;
        }
        used = 0ull;
        for (int it = 0; it < 8; ++it) {
            int best = -1; float bv = -INFINITY;
            for (int i = 0; i < 64; ++i)
                if (!((used >> i) & 1ull) && sc[i] > bv) { bv = sc[i]; best = i; }
            if (best < 0) best = it;
            used |= 1ull << best;
            topw[bh * 8 + it] = best;
        }
    }
}

// ---------------- gather pruned K (normalized) -----------------------------
// ksel layout: [bh][tok(64)][d(64)]. k layout: (b, 512, 4096).
__global__ __launch_bounds__(256) void gather_k_kernel(
    const float* __restrict__ k, const float* __restrict__ invnk,
    const int* __restrict__ toph, const int* __restrict__ topw,
    float* __restrict__ ksel)
{
    int bh = blockIdx.x, b = bh >> 3, h = bh & 7;
    __shared__ int th_s[8], tw_s[8];
    if (threadIdx.x < 8) th_s[threadIdx.x] = toph[bh * 8 + threadIdx.x];
    else if (threadIdx.x < 16) tw_s[threadIdx.x - 8] = topw[bh * 8 + threadIdx.x - 8];
    __syncthreads();
    const float* kbase = k + ((size_t)b * 512 + (size_t)h * 64) * 4096;
    for (int l = threadIdx.x; l < 4096; l += 256) {
        int tok = l >> 6, d = l & 63;
        int p = th_s[tok >> 3] * 64 + tw_s[tok & 7];
        ksel[(size_t)bh * 4096 + l] = kbase[(size_t)d * 4096 + p] * invnk[(size_t)bh * 4096 + p];
    }
}

// ---------------- compute V only at gathered positions --------------------
// vsel[bh][tok][d] = sum_c w_kv[512 + h*64 + d][c] * ctx_n[b][c][p_tok]
__global__ __launch_bounds__(256) void vsel_kernel(
    const float* __restrict__ w_kv, const float* __restrict__ ctxn,
    const int* __restrict__ toph, const int* __restrict__ topw,
    float* __restrict__ vsel)
{
    int bh = blockIdx.x, b = bh >> 3, h = bh & 7;
    __shared__ int th_s[8], tw_s[8];
    if (threadIdx.x < 8) th_s[threadIdx.x] = toph[bh * 8 + threadIdx.x];
    else if (threadIdx.x < 16) tw_s[threadIdx.x - 8] = topw[bh * 8 + threadIdx.x - 8];
    __syncthreads();
    const float* cb = ctxn + (size_t)b * 256 * 4096;
    for (int l = threadIdx.x; l < 4096; l += 256) {
        int tok = l >> 6, d = l & 63;
        int p = th_s[tok >> 3] * 64 + tw_s[tok & 7];
        const float* wr = w_kv + (size_t)(512 + h * 64 + d) * 256;
        float s = 0.f;
        for (int c = 0; c < 256; ++c) s += wr[c] * cb[(size_t)c * 4096 + p];
        vsel[(size_t)bh * 4096 + l] = s;
    }
}

// ---------------- fused cosine-sim attention, in-place over q ------------
// q: (bh, 64, 9216). q,k unit vectors -> sim in [-1,1] -> fixed softmax
// shift of 1.0 replaces the max pass (softmax is shift-invariant).
__global__ __launch_bounds__(256) void attn_kernel(
    float* __restrict__ q, const float* __restrict__ ksel,
    const float* __restrict__ vsel)
{
    int bh = blockIdx.y;
    int p = blockIdx.x * 256 + threadIdx.x;
    __shared__ float Ks[4096], Vs[4096];
    for (int l = threadIdx.x; l < 4096; l += 256) {
        Ks[l] = ksel[(size_t)bh * 4096 + l];
        Vs[l] = vsel[(size_t)bh * 4096 + l];
    }
    __syncthreads();
    float* qcol = q + (size_t)bh * 64 * 9216 + p;
    float qr[64];
    float ss = 0.f;
    #pragma unroll
    for (int d = 0; d < 64; ++d) { float v = qcol[(size_t)d * 9216]; qr[d] = v; ss += v * v; }
    float inv = 1.f / fmaxf(sqrtf(ss), 1e-12f);
    #pragma unroll
    for (int d = 0; d < 64; ++d) qr[d] *= inv;
    float acc[64];
    #pragma unroll
    for (int d = 0; d < 64; ++d) acc[d] = 0.f;
    float denom = 0.f;
    for (int tt = 0; tt < 64; ++tt) {
        const float* kr = Ks + tt * 64;
        float s = 0.f;
        #pragma unroll
        for (int d = 0; d < 64; ++d) s += qr[d] * kr[d];
        float e = __expf(s - 1.f);
        denom += e;
        const float* vr = Vs + tt * 64;
        #pragma unroll
        for (int d = 0; d < 64; ++d) acc[d] += e * vr[d];
    }
    float rd = 1.f / denom;
    #pragma unroll
    for (int d = 0; d < 64; ++d) qcol[(size_t)d * 9216] = acc[d] * rd;
}

// ---------------- final: chan_norm + gamma*out + residual ----------------
__global__ __launch_bounds__(256) void final_kernel(
    const float* __restrict__ xin, const float* __restrict__ g,
    const float* __restrict__ bb, const float* __restrict__ gamma,
    const float* __restrict__ qsrc, float* __restrict__ out)
{
    int idx = blockIdx.x * 256 + threadIdx.x;  // b*9216 + p
    int b = idx / 9216, p = idx - b * 9216;
    const float* xb = xin + (size_t)b * 256 * 9216 + p;
    float mean = 0.f, m2 = 0.f;
    for (int c = 0; c < 256; ++c) {
        float v = xb[(size_t)c * 9216];
        mean += v; m2 += v * v;
    }
    mean *= (1.f / 256.f); m2 *= (1.f / 256.f);
    float inv = 1.f / sqrtf(m2 - mean * mean + EPSN);
    float gm = gamma[0];
    const float* qs = qsrc + (size_t)b * 256 * 9216 + p;
    float* ob = out + (size_t)b * 256 * 9216 + p;
    for (int c = 0; c < 256; ++c) {
        float v = (xb[(size_t)c * 9216] - mean) * inv * g[c] + bb[c];
        ob[(size_t)c * 9216] = gm * v + qs[(size_t)c * 9216];
    }
}

extern "C" void kernel_launch(void* const* d_in, const int* in_sizes, int n_in,
                              void* d_out, int out_size, void* d_ws, size_t ws_size,
                              hipStream_t stream) {
    const float* qsrc  = (const float*)d_in[0];
    const float* ctx   = (const float*)d_in[1];
    const float* qs_g  = (const float*)d_in[2];
    const float* qs_b  = (const float*)d_in[3];
    const float* ctx_g = (const float*)d_in[4];
    const float* ctx_b = (const float*)d_in[5];
    const float* out_g = (const float*)d_in[6];
    const float* out_b = (const float*)d_in[7];
    const float* w_q   = (const float*)d_in[8];
    const float* w_kv  = (const float*)d_in[9];
    const float* w_out = (const float*)d_in[10];
    const float* gamma = (const float*)d_in[11];
    float* out = (float*)d_out;
    float* ws = (float*)d_ws;

    // Workspace (floats), 223 MiB total:
    //   SlotA: qs_n (8*256*9216) -> k (8*512*4096) -> out_pre (8*256*9216)
    //   SlotB: q (8*512*9216), attention output in-place
    //   ctx_n (8*256*4096) lives in d_out (overwritten by final_kernel last)
    float* SlotA = ws;                     // 18,874,368 floats
    float* SlotB = SlotA + 18874368;       // 37,748,736 floats
    float* S     = SlotB + 37748736;
    float* invnq = S;                      // 589,824
    float* invnk = invnq + 589824;         // 262,144
    float* krow  = invnk + 262144;         // 262,144
    float* kcol  = krow + 262144;          // 262,144
    float* qprob = kcol + 262144;          // 4,096
    float* ksel  = qprob + 4096;           // 262,144
    float* vsel  = ksel + 262144;          // 262,144
    int*   toph  = (int*)(vsel + 262144);  // 512
    int*   topw  = toph + 512;             // 512
    float* ctxn  = out;                    // staged in d_out

    // 1. qs_n = chan_norm(query_source)  -> SlotA
    chan_norm_kernel<<<288, 256, 0, stream>>>(qsrc, qs_g, qs_b, SlotA, 9216);
    // 2. q = w_q @ qs_n -> SlotB (b, 512, 9216) == (bh, 64, 9216)
    gemm_fp32<<<dim3(144, 8, 8), 256, 0, stream>>>(w_q, SlotA, SlotB, 512, 9216, 256,
                                                   256LL * 9216, 512LL * 9216);
    // 3. ctx_n = chan_norm(context) -> d_out
    chan_norm_kernel<<<128, 256, 0, stream>>>(ctx, ctx_g, ctx_b, ctxn, 4096);
    // 4. k = w_kv[0:512] @ ctx_n -> SlotA (qs_n dead)
    gemm_fp32<<<dim3(64, 8, 8), 256, 0, stream>>>(w_kv, ctxn, SlotA, 512, 4096, 256,
                                                  256LL * 4096, 512LL * 4096);
    // 5-6. inverse l2 norms of q and k
    l2inv_kernel<<<2304, 256, 0, stream>>>(SlotB, invnq, 9216, 512LL * 9216, 64LL * 9216);
    l2inv_kernel<<<1024, 256, 0, stream>>>(SlotA, invnk, 4096, 512LL * 4096, 64LL * 4096);
    // 7. |k_n| row/col marginals
    krowcol_kernel<<<64, 256, 0, stream>>>(SlotA, invnk, krow, kcol);
    // 8. q_probe
    qprobe_kernel<<<4096, 256, 0, stream>>>(SlotB, invnq, qprob);
    // 9. top-8 rows/cols
    topk_kernel<<<64, 64, 0, stream>>>(qprob, krow, kcol, toph, topw);
    // 10. gather pruned normalized K
    gather_k_kernel<<<64, 256, 0, stream>>>(SlotA, invnk, toph, topw, ksel);
    // 11. V at gathered positions only (w_kv rows 512..1023 @ ctx_n cols)
    vsel_kernel<<<64, 256, 0, stream>>>(w_kv, ctxn, toph, topw, vsel);
    // 12. fused attention (l2norm(q) + sim + softmax + PV), in-place on SlotB
    attn_kernel<<<dim3(36, 64), 256, 0, stream>>>(SlotB, ksel, vsel);
    // 13. out_pre = w_out @ attn_out -> SlotA (k dead)
    gemm_fp32<<<dim3(144, 4, 8), 256, 0, stream>>>(w_out, SlotB, SlotA, 256, 9216, 512,
                                                   512LL * 9216, 256LL * 9216);
    // 14. final chan_norm + gamma*out + residual -> d_out (ctx_n dead)
    final_kernel<<<288, 256, 0, stream>>>(SlotA, out_g, out_b, gamma, qsrc, out);
}

// Round 4
// 928.120 us; speedup vs baseline: 2.3579x; 2.3579x over previous
//
#include <hip/hip_runtime.h>
#include <math.h>

// DPCA2D: dual-pruned cosine-sim cross-attention.
// B=8, C=256, Nq=9216 (96x96), Nc=4096 (64x64), INNER=512, HEADS=8, D=64,
// BH=64, top-k 8x8 -> 64 kept tokens.
//
// Round 4: selection-critical q,k GEMMs -> split-bf16 (bf16x3) MFMA, ~1e-5
// relative error (round-3's plain bf16 at 2e-3 flipped top-k selections).
// q GEMM epilogue fuses l2-norm + q_probe from fp32 accumulators and stores
// pre-normalized bf16 q. k stays fp32 out; selection path = round-2 semantics.

#define EPSN 1e-5f

typedef __attribute__((ext_vector_type(8))) short bf16x8;
typedef __attribute__((ext_vector_type(4))) float f32x4;

__device__ inline unsigned short f2bf(float f) {
    unsigned u = __float_as_uint(f);
    u += 0x7fff + ((u >> 16) & 1);          // RNE
    return (unsigned short)(u >> 16);
}
__device__ inline float bf2f(unsigned short h) {
    return __uint_as_float((unsigned)h << 16);
}

#define GL2LDS(g, s) __builtin_amdgcn_global_load_lds( \
    (const __attribute__((address_space(1))) void*)(g), \
    (__attribute__((address_space(3))) void*)(s), 16, 0, 0)

// ---------------- fp32 -> bf16 hi/lo split (weights) ----------------
__global__ __launch_bounds__(256) void cvt_split_kernel(
    const float* __restrict__ x, unsigned short* __restrict__ hi,
    unsigned short* __restrict__ lo, int n)
{
    int i = blockIdx.x * 256 + threadIdx.x;
    if (i < n) {
        float v = x[i];
        unsigned short h = f2bf(v);
        hi[i] = h;
        lo[i] = f2bf(v - bf2f(h));
    }
}
__global__ __launch_bounds__(256) void cvt_bf16_kernel(
    const float* __restrict__ x, unsigned short* __restrict__ y, int n)
{
    int i = blockIdx.x * 256 + threadIdx.x;
    if (i < n) y[i] = f2bf(x[i]);
}

// ---------------- channel LayerNorm -> transposed bf16 hi/lo ------------
// x: (B,256,N) fp32 -> yh/yl: (B,N,256) bf16 (k-contiguous rows).
__global__ __launch_bounds__(256) void chan_norm_split_kernel(
    const float* __restrict__ x, const float* __restrict__ g,
    const float* __restrict__ bb, unsigned short* __restrict__ yh,
    unsigned short* __restrict__ yl, int N)
{
    int idx = blockIdx.x * 256 + threadIdx.x;
    int b = idx / N, p = idx - b * N;
    const float* xb = x + (size_t)b * 256 * N + p;
    float mean = 0.f, m2 = 0.f;
    for (int c = 0; c < 256; ++c) {
        float v = xb[(size_t)c * N];
        mean += v; m2 += v * v;
    }
    mean *= (1.f / 256.f); m2 *= (1.f / 256.f);
    float inv = 1.f / sqrtf(m2 - mean * mean + EPSN);
    uint4* yhr = (uint4*)(yh + ((size_t)b * N + p) * 256);
    uint4* ylr = (uint4*)(yl + ((size_t)b * N + p) * 256);
    for (int c0 = 0; c0 < 256; c0 += 8) {
        unsigned short hh[8], ll[8];
        #pragma unroll
        for (int j = 0; j < 8; ++j) {
            int c = c0 + j;
            float v = (xb[(size_t)c * N] - mean) * inv * g[c] + bb[c];
            hh[j] = f2bf(v);
            ll[j] = f2bf(v - bf2f(hh[j]));
        }
        uint4 ph, pl;
        ph.x = (unsigned)hh[0] | ((unsigned)hh[1] << 16);
        ph.y = (unsigned)hh[2] | ((unsigned)hh[3] << 16);
        ph.z = (unsigned)hh[4] | ((unsigned)hh[5] << 16);
        ph.w = (unsigned)hh[6] | ((unsigned)hh[7] << 16);
        pl.x = (unsigned)ll[0] | ((unsigned)ll[1] << 16);
        pl.y = (unsigned)ll[2] | ((unsigned)ll[3] << 16);
        pl.z = (unsigned)ll[4] | ((unsigned)ll[5] << 16);
        pl.w = (unsigned)ll[6] | ((unsigned)ll[7] << 16);
        yhr[c0 >> 3] = ph;
        ylr[c0 >> 3] = pl;
    }
}

// ---------------- split-bf16 MFMA GEMM: C = A @ Bt^T (x3 passes) ---------
// A hi/lo: MxK. Bt hi/lo: NxK (activations^T, per-z). 128x128 tile, BK=32.
// MODE 0: fp32 C. MODE 1: fused q epilogue — store q_n bf16 into (z,M,N)
//   layout + atomicAdd qprobe[bh][d] (+= sum_cols q*inv), norms from fp32 acc.
template <int MODE>
__global__ __launch_bounds__(256) void gemm_x3(
    const unsigned short* __restrict__ Ah, const unsigned short* __restrict__ Al,
    const unsigned short* __restrict__ Bth, const unsigned short* __restrict__ Btl,
    void* __restrict__ Cv, float* __restrict__ qprobe,
    int M, int N, int K, long long strideBt, long long strideC)
{
    __shared__ unsigned short AsH[128 * 32], AsL[128 * 32];
    __shared__ unsigned short BsH[128 * 32], BsL[128 * 32];
    const unsigned short* BzH = Bth + (size_t)blockIdx.z * strideBt;
    const unsigned short* BzL = Btl + (size_t)blockIdx.z * strideBt;
    int n0 = blockIdx.x * 128, m0 = blockIdx.y * 128;
    int t = threadIdx.x;
    int w = t >> 6, l = t & 63;
    int wm = (w >> 1) * 64, wn = (w & 1) * 64;
    int lc = l & 15, quad = l >> 4;

    f32x4 acc[4][4];
    #pragma unroll
    for (int i = 0; i < 4; ++i)
        #pragma unroll
        for (int j = 0; j < 4; ++j) acc[i][j] = {0.f, 0.f, 0.f, 0.f};

    int srow = t >> 2;
    int sseg = (t & 3) * 8;
    for (int k0 = 0; k0 < K; k0 += 32) {
        size_t a0 = (size_t)(m0 + srow) * K + k0 + sseg;
        size_t a1 = (size_t)(m0 + 64 + srow) * K + k0 + sseg;
        size_t b0 = (size_t)(n0 + srow) * K + k0 + sseg;
        size_t b1 = (size_t)(n0 + 64 + srow) * K + k0 + sseg;
        __syncthreads();
        GL2LDS(Ah + a0, AsH + (size_t)t * 8);
        GL2LDS(Ah + a1, AsH + 2048 + (size_t)t * 8);
        GL2LDS(Al + a0, AsL + (size_t)t * 8);
        GL2LDS(Al + a1, AsL + 2048 + (size_t)t * 8);
        GL2LDS(BzH + b0, BsH + (size_t)t * 8);
        GL2LDS(BzH + b1, BsH + 2048 + (size_t)t * 8);
        GL2LDS(BzL + b0, BsL + (size_t)t * 8);
        GL2LDS(BzL + b1, BsL + 2048 + (size_t)t * 8);
        __syncthreads();
        bf16x8 ah[4], al_[4], bh_[4], bl_[4];
        #pragma unroll
        for (int i = 0; i < 4; ++i) {
            ah[i]  = *(const bf16x8*)(AsH + (size_t)(wm + i * 16 + lc) * 32 + quad * 8);
            al_[i] = *(const bf16x8*)(AsL + (size_t)(wm + i * 16 + lc) * 32 + quad * 8);
        }
        #pragma unroll
        for (int j = 0; j < 4; ++j) {
            bh_[j] = *(const bf16x8*)(BsH + (size_t)(wn + j * 16 + lc) * 32 + quad * 8);
            bl_[j] = *(const bf16x8*)(BsL + (size_t)(wn + j * 16 + lc) * 32 + quad * 8);
        }
        #pragma unroll
        for (int i = 0; i < 4; ++i)
            #pragma unroll
            for (int j = 0; j < 4; ++j) {
                acc[i][j] = __builtin_amdgcn_mfma_f32_16x16x32_bf16(al_[i], bh_[j], acc[i][j], 0, 0, 0);
                acc[i][j] = __builtin_amdgcn_mfma_f32_16x16x32_bf16(ah[i],  bl_[j], acc[i][j], 0, 0, 0);
                acc[i][j] = __builtin_amdgcn_mfma_f32_16x16x32_bf16(ah[i],  bh_[j], acc[i][j], 0, 0, 0);
            }
    }
    // C/D layout: col=lane&15, row=quad*4+reg (m89-verified)
    if (MODE == 0) {
        float* C = (float*)Cv;
        size_t cbase = (size_t)blockIdx.z * strideC;
        #pragma unroll
        for (int i = 0; i < 4; ++i)
            #pragma unroll
            for (int j = 0; j < 4; ++j)
                #pragma unroll
                for (int r = 0; r < 4; ++r) {
                    int row = m0 + wm + i * 16 + quad * 4 + r;
                    int col = n0 + wn + j * 16 + lc;
                    C[cbase + (size_t)row * N + col] = acc[i][j][r];
                }
    } else {
        // wave's 64 M-rows = one full head (d 0..63): exact column norms in-wave
        float inv[4];
        #pragma unroll
        for (int j = 0; j < 4; ++j) {
            float s = 0.f;
            #pragma unroll
            for (int i = 0; i < 4; ++i)
                #pragma unroll
                for (int r = 0; r < 4; ++r) s += acc[i][j][r] * acc[i][j][r];
            s += __shfl_xor(s, 16);
            s += __shfl_xor(s, 32);
            inv[j] = 1.f / fmaxf(sqrtf(s), 1e-12f);
        }
        unsigned short* qbf = (unsigned short*)Cv;
        size_t cbase = (size_t)blockIdx.z * strideC;
        #pragma unroll
        for (int i = 0; i < 4; ++i)
            #pragma unroll
            for (int j = 0; j < 4; ++j)
                #pragma unroll
                for (int r = 0; r < 4; ++r) {
                    int row = m0 + wm + i * 16 + quad * 4 + r;
                    int col = n0 + wn + j * 16 + lc;
                    qbf[cbase + (size_t)row * N + col] = f2bf(acc[i][j][r] * inv[j]);
                }
        int bh = blockIdx.z * 8 + ((m0 + wm) >> 6);
        #pragma unroll
        for (int i = 0; i < 4; ++i)
            #pragma unroll
            for (int r = 0; r < 4; ++r) {
                float s = 0.f;
                #pragma unroll
                for (int j = 0; j < 4; ++j) s += acc[i][j][r] * inv[j];
                s += __shfl_xor(s, 1);
                s += __shfl_xor(s, 2);
                s += __shfl_xor(s, 4);
                s += __shfl_xor(s, 8);
                if (lc == 0)
                    atomicAdd(&qprobe[bh * 64 + i * 16 + quad * 4 + r], s);
            }
    }
}

// ---------------- plain bf16 MFMA GEMM (value path: out projection) ------
__global__ __launch_bounds__(256) void gemm_mfma(
    const unsigned short* __restrict__ A, const unsigned short* __restrict__ Bt,
    float* __restrict__ C, int M, int N, int K,
    long long strideBt, long long strideC)
{
    __shared__ unsigned short As[128 * 32];
    __shared__ unsigned short Bs[128 * 32];
    const unsigned short* Bz = Bt + (size_t)blockIdx.z * strideBt;
    int n0 = blockIdx.x * 128, m0 = blockIdx.y * 128;
    int t = threadIdx.x;
    int w = t >> 6, l = t & 63;
    int wm = (w >> 1) * 64, wn = (w & 1) * 64;
    int lc = l & 15, quad = l >> 4;
    f32x4 acc[4][4];
    #pragma unroll
    for (int i = 0; i < 4; ++i)
        #pragma unroll
        for (int j = 0; j < 4; ++j) acc[i][j] = {0.f, 0.f, 0.f, 0.f};
    int srow = t >> 2, sseg = (t & 3) * 8;
    for (int k0 = 0; k0 < K; k0 += 32) {
        const unsigned short* ga0 = A  + (size_t)(m0 + srow)      * K + k0 + sseg;
        const unsigned short* ga1 = A  + (size_t)(m0 + 64 + srow) * K + k0 + sseg;
        const unsigned short* gb0 = Bz + (size_t)(n0 + srow)      * K + k0 + sseg;
        const unsigned short* gb1 = Bz + (size_t)(n0 + 64 + srow) * K + k0 + sseg;
        __syncthreads();
        GL2LDS(ga0, As + (size_t)t * 8);
        GL2LDS(ga1, As + 2048 + (size_t)t * 8);
        GL2LDS(gb0, Bs + (size_t)t * 8);
        GL2LDS(gb1, Bs + 2048 + (size_t)t * 8);
        __syncthreads();
        bf16x8 af[4], bfr[4];
        #pragma unroll
        for (int i = 0; i < 4; ++i)
            af[i] = *(const bf16x8*)(As + (size_t)(wm + i * 16 + lc) * 32 + quad * 8);
        #pragma unroll
        for (int j = 0; j < 4; ++j)
            bfr[j] = *(const bf16x8*)(Bs + (size_t)(wn + j * 16 + lc) * 32 + quad * 8);
        #pragma unroll
        for (int i = 0; i < 4; ++i)
            #pragma unroll
            for (int j = 0; j < 4; ++j)
                acc[i][j] = __builtin_amdgcn_mfma_f32_16x16x32_bf16(af[i], bfr[j], acc[i][j], 0, 0, 0);
    }
    size_t cbase = (size_t)blockIdx.z * strideC;
    #pragma unroll
    for (int i = 0; i < 4; ++i)
        #pragma unroll
        for (int j = 0; j < 4; ++j)
            #pragma unroll
            for (int r = 0; r < 4; ++r) {
                int row = m0 + wm + i * 16 + quad * 4 + r;
                int col = n0 + wn + j * 16 + lc;
                C[cbase + (size_t)row * N + col] = acc[i][j][r];
            }
}

// ---------------- l2 inverse norm (fp32 k) ----------------
__global__ __launch_bounds__(256) void l2inv_f32_kernel(
    const float* __restrict__ x, float* __restrict__ inv, int N,
    long long strideB, long long strideH)
{
    int idx = blockIdx.x * 256 + threadIdx.x;
    int bh = idx / N, p = idx - bh * N;
    const float* base = x + (size_t)(bh >> 3) * strideB + (size_t)(bh & 7) * strideH + p;
    float ss = 0.f;
    #pragma unroll 8
    for (int d = 0; d < 64; ++d) { float v = base[(size_t)d * N]; ss += v * v; }
    inv[idx] = 1.f / fmaxf(sqrtf(ss), 1e-12f);
}

// ---------------- row/col sums of |k_n| per bh ---------------------------
__global__ __launch_bounds__(256) void krowcol_kernel(
    const float* __restrict__ k, const float* __restrict__ invnk,
    float* __restrict__ krow, float* __restrict__ kcol)
{
    int bh = blockIdx.x, b = bh >> 3, h = bh & 7;
    int d0 = blockIdx.y * 8;
    const float* kbase = k + ((size_t)b * 512 + (size_t)h * 64) * 4096;
    __shared__ float inv_s[4096];
    __shared__ float tile[64 * 65];
    int t = threadIdx.x;
    for (int l = t; l < 4096; l += 256) inv_s[l] = invnk[(size_t)bh * 4096 + l];
    for (int dd = 0; dd < 8; ++dd) {
        int d = d0 + dd;
        __syncthreads();
        for (int l = t; l < 4096; l += 256)
            tile[(l >> 6) * 65 + (l & 63)] = kbase[(size_t)d * 4096 + l];
        __syncthreads();
        if (t < 64) {
            float s = 0.f;
            for (int ww = 0; ww < 64; ++ww) s += fabsf(tile[t * 65 + ww]) * inv_s[t * 64 + ww];
            krow[((size_t)bh * 64 + d) * 64 + t] = s;
        } else if (t < 128) {
            int ww = t - 64;
            float s = 0.f;
            for (int hh = 0; hh < 64; ++hh) s += fabsf(tile[hh * 65 + ww]) * inv_s[hh * 64 + ww];
            kcol[((size_t)bh * 64 + d) * 64 + ww] = s;
        }
    }
}

// ---------------- top-8 row/col selection per bh -------------------------
__global__ void topk_kernel(const float* __restrict__ qprobe,
                            const float* __restrict__ krow,
                            const float* __restrict__ kcol,
                            int* __restrict__ toph, int* __restrict__ topw)
{
    int bh = blockIdx.x, t = threadIdx.x;  // 64 threads
    __shared__ float qp[64], sr[64], sc[64];
    qp[t] = qprobe[bh * 64 + t];
    __syncthreads();
    float s1 = 0.f, s2 = 0.f;
    for (int d = 0; d < 64; ++d) {
        float qv = qp[d];
        s1 += qv * krow[((size_t)bh * 64 + d) * 64 + t];
        s2 += qv * kcol[((size_t)bh * 64 + d) * 64 + t];
    }
    sr[t] = s1; sc[t] = s2;
    __syncthreads();
    if (t == 0) {
        unsigned long long used = 0ull;
        for (int it = 0; it < 8; ++it) {
            int best = -1; float bv = -INFINITY;
            for (int i = 0; i < 64; ++i)
                if (!((used >> i) & 1ull) && sr[i] > bv) { bv = sr[i]; best = i; }
            if (best < 0) best = it;
            used |= 1ull << best;
            toph[bh * 8 + it] = best;
        }
        used = 0ull;
        for (int it = 0; it < 8; ++it) {
            int best = -1; float bv = -INFINITY;
            for (int i = 0; i < 64; ++i)
                if (!((used >> i) & 1ull) && sc[i] > bv) { bv = sc[i]; best = i; }
            if (best < 0) best = it;
            used |= 1ull << best;
            topw[bh * 8 + it] = best;
        }
    }
}

// ---------------- gather pruned normalized K (fp32) ----------------------
__global__ __launch_bounds__(256) void gather_k_kernel(
    const float* __restrict__ k, const float* __restrict__ invnk,
    const int* __restrict__ toph, const int* __restrict__ topw,
    float* __restrict__ ksel)
{
    int bh = blockIdx.x, b = bh >> 3, h = bh & 7;
    __shared__ int th_s[8], tw_s[8];
    if (threadIdx.x < 8) th_s[threadIdx.x] = toph[bh * 8 + threadIdx.x];
    else if (threadIdx.x < 16) tw_s[threadIdx.x - 8] = topw[bh * 8 + threadIdx.x - 8];
    __syncthreads();
    const float* kbase = k + ((size_t)b * 512 + (size_t)h * 64) * 4096;
    for (int l = threadIdx.x; l < 4096; l += 256) {
        int tok = l >> 6, d = l & 63;
        int p = th_s[tok >> 3] * 64 + tw_s[tok & 7];
        ksel[(size_t)bh * 4096 + l] = kbase[(size_t)d * 4096 + p] * invnk[(size_t)bh * 4096 + p];
    }
}

// ---------------- V at gathered positions (bf16 ctx hi, fp32 w) ----------
__global__ __launch_bounds__(256) void vsel_kernel(
    const float* __restrict__ w_kv, const unsigned short* __restrict__ ctxt,
    const int* __restrict__ toph, const int* __restrict__ topw,
    float* __restrict__ vsel)
{
    int bh = blockIdx.x, b = bh >> 3, h = bh & 7;
    __shared__ int th_s[8], tw_s[8];
    if (threadIdx.x < 8) th_s[threadIdx.x] = toph[bh * 8 + threadIdx.x];
    else if (threadIdx.x < 16) tw_s[threadIdx.x - 8] = topw[bh * 8 + threadIdx.x - 8];
    __syncthreads();
    const unsigned short* cb = ctxt + (size_t)b * 4096 * 256;
    int l = blockIdx.y * 1024 + threadIdx.x;
    for (int it = 0; it < 4; ++it, l += 256) {
        int tok = l >> 6, d = l & 63;
        int p = th_s[tok >> 3] * 64 + tw_s[tok & 7];
        const float* wr = w_kv + (size_t)(512 + h * 64 + d) * 256;
        const unsigned short* cr = cb + (size_t)p * 256;
        float s = 0.f;
        for (int c = 0; c < 256; ++c) s += wr[c] * bf2f(cr[c]);
        vsel[(size_t)bh * 4096 + l] = s;
    }
}

// ---------------- fused attention (q pre-normalized bf16) ----------------
// q_n: (bh,64,9216) bf16. Fixed softmax shift 1.0 (unit q,k => sim<=1).
__global__ __launch_bounds__(256) void attn_kernel(
    const unsigned short* __restrict__ q, const float* __restrict__ ksel,
    const float* __restrict__ vsel, unsigned short* __restrict__ attn_t)
{
    int bh = blockIdx.y;
    int p = blockIdx.x * 256 + threadIdx.x;
    __shared__ float Ks[4096], Vs[4096];
    for (int l = threadIdx.x; l < 4096; l += 256) {
        Ks[l] = ksel[(size_t)bh * 4096 + l];
        Vs[l] = vsel[(size_t)bh * 4096 + l];
    }
    __syncthreads();
    const unsigned short* qcol = q + (size_t)bh * 64 * 9216 + p;
    float qr[64];
    #pragma unroll
    for (int d = 0; d < 64; ++d) qr[d] = bf2f(qcol[(size_t)d * 9216]);
    float acc[64];
    #pragma unroll
    for (int d = 0; d < 64; ++d) acc[d] = 0.f;
    float denom = 0.f;
    for (int tt = 0; tt < 64; ++tt) {
        const float* kr = Ks + tt * 64;
        float s = 0.f;
        #pragma unroll
        for (int d = 0; d < 64; ++d) s += qr[d] * kr[d];
        float e = __expf(s - 1.f);
        denom += e;
        const float* vr = Vs + tt * 64;
        #pragma unroll
        for (int d = 0; d < 64; ++d) acc[d] += e * vr[d];
    }
    float rd = 1.f / denom;
    unsigned* op = (unsigned*)(attn_t + ((size_t)(bh >> 3) * 9216 + p) * 512 + (bh & 7) * 64);
    #pragma unroll
    for (int d = 0; d < 64; d += 2) {
        unsigned u = (unsigned)f2bf(acc[d] * rd) | ((unsigned)f2bf(acc[d + 1] * rd) << 16);
        op[d >> 1] = u;
    }
}

// ---------------- final: chan_norm + gamma*out + residual (in-place) -----
__global__ __launch_bounds__(256) void final_kernel(
    const float* __restrict__ g, const float* __restrict__ bb,
    const float* __restrict__ gamma, const float* __restrict__ qsrc,
    float* __restrict__ out)
{
    int idx = blockIdx.x * 256 + threadIdx.x;  // b*9216 + p
    int b = idx / 9216, p = idx - b * 9216;
    float* xb = out + (size_t)b * 256 * 9216 + p;
    float mean = 0.f, m2 = 0.f;
    for (int c = 0; c < 256; ++c) {
        float v = xb[(size_t)c * 9216];
        mean += v; m2 += v * v;
    }
    mean *= (1.f / 256.f); m2 *= (1.f / 256.f);
    float inv = 1.f / sqrtf(m2 - mean * mean + EPSN);
    float gm = gamma[0];
    const float* qs = qsrc + (size_t)b * 256 * 9216 + p;
    for (int c = 0; c < 256; ++c) {
        float v = (xb[(size_t)c * 9216] - mean) * inv * g[c] + bb[c];
        xb[(size_t)c * 9216] = gm * v + qs[(size_t)c * 9216];
    }
}

extern "C" void kernel_launch(void* const* d_in, const int* in_sizes, int n_in,
                              void* d_out, int out_size, void* d_ws, size_t ws_size,
                              hipStream_t stream) {
    const float* qsrc  = (const float*)d_in[0];
    const float* ctx   = (const float*)d_in[1];
    const float* qs_g  = (const float*)d_in[2];
    const float* qs_b  = (const float*)d_in[3];
    const float* ctx_g = (const float*)d_in[4];
    const float* ctx_b = (const float*)d_in[5];
    const float* out_g = (const float*)d_in[6];
    const float* out_b = (const float*)d_in[7];
    const float* w_q   = (const float*)d_in[8];
    const float* w_kv  = (const float*)d_in[9];
    const float* w_out = (const float*)d_in[10];
    const float* gamma = (const float*)d_in[11];
    float* out = (float*)d_out;

    // ---- workspace (bytes), peak ~191 MB, liveness-aliased ----
    // Region A @0 (75,497,472): qs_h+qs_l [1->2] ; k_f fp32 [4->10] ; attn_t [11->12]
    // Region B @75,497,472 (75,497,472): q_n bf16 (b,512,9216) [2->11]
    // Region C @150,994,944 (33,554,432): ctx_h+ctx_l [3->10]
    char* base = (char*)d_ws;
    unsigned short* qs_h  = (unsigned short*)(base + 0);
    unsigned short* qs_l  = (unsigned short*)(base + 37748736);
    float*          k_f   = (float*)        (base + 0);
    unsigned short* attn_t= (unsigned short*)(base + 0);
    unsigned short* q_bf  = (unsigned short*)(base + 75497472);
    unsigned short* ctx_h = (unsigned short*)(base + 150994944);
    unsigned short* ctx_l = (unsigned short*)(base + 167772160);
    char* S = base + 184549376;
    float* invnk = (float*)S;                     S += 262144 * 4;
    float* krow  = (float*)S;                     S += 262144 * 4;
    float* kcol  = (float*)S;                     S += 262144 * 4;
    float* qprob = (float*)S;                     S += 4096 * 4;
    float* ksel  = (float*)S;                     S += 262144 * 4;
    float* vsel  = (float*)S;                     S += 262144 * 4;
    int*   toph  = (int*)S;                       S += 512 * 4;
    int*   topw  = (int*)S;                       S += 512 * 4;
    unsigned short* wq_h = (unsigned short*)S;    S += 131072 * 2;
    unsigned short* wq_l = (unsigned short*)S;    S += 131072 * 2;
    unsigned short* wk_h = (unsigned short*)S;    S += 131072 * 2;
    unsigned short* wk_l = (unsigned short*)S;    S += 131072 * 2;
    unsigned short* wo_h = (unsigned short*)S;    S += 131072 * 2;

    // 0. weight splits (w_kv: only k-half rows 0..511 used in GEMM)
    cvt_split_kernel<<<512, 256, 0, stream>>>(w_q, wq_h, wq_l, 131072);
    cvt_split_kernel<<<512, 256, 0, stream>>>(w_kv, wk_h, wk_l, 131072);
    cvt_bf16_kernel<<<512, 256, 0, stream>>>(w_out, wo_h, 131072);
    hipMemsetAsync(qprob, 0, 4096 * sizeof(float), stream);
    // 1. qs hi/lo = chan_norm(query_source)^T
    chan_norm_split_kernel<<<288, 256, 0, stream>>>(qsrc, qs_g, qs_b, qs_h, qs_l, 9216);
    // 2. q = w_q @ qs (bf16x3) -> q_n bf16 + qprobe (fused epilogue)
    gemm_x3<1><<<dim3(72, 4, 8), 256, 0, stream>>>(
        wq_h, wq_l, qs_h, qs_l, q_bf, qprob, 512, 9216, 256,
        9216LL * 256, 512LL * 9216);
    // 3. ctx hi/lo = chan_norm(context)^T
    chan_norm_split_kernel<<<128, 256, 0, stream>>>(ctx, ctx_g, ctx_b, ctx_h, ctx_l, 4096);
    // 4. k = w_kv[0:512] @ ctx (bf16x3) -> fp32 (qs region dead)
    gemm_x3<0><<<dim3(32, 4, 8), 256, 0, stream>>>(
        wk_h, wk_l, ctx_h, ctx_l, k_f, nullptr, 512, 4096, 256,
        4096LL * 256, 512LL * 4096);
    // 5. inverse l2 norms of k
    l2inv_f32_kernel<<<1024, 256, 0, stream>>>(k_f, invnk, 4096, 512LL * 4096, 64LL * 4096);
    // 6. |k_n| row/col marginals
    krowcol_kernel<<<dim3(64, 8), 256, 0, stream>>>(k_f, invnk, krow, kcol);
    // 7. top-8 rows/cols
    topk_kernel<<<64, 64, 0, stream>>>(qprob, krow, kcol, toph, topw);
    // 8. gather pruned normalized K
    gather_k_kernel<<<64, 256, 0, stream>>>(k_f, invnk, toph, topw, ksel);
    // 9. V at gathered positions
    vsel_kernel<<<dim3(64, 4), 256, 0, stream>>>(w_kv, ctx_h, toph, topw, vsel);
    // 10. fused attention -> attn_t bf16 (b,9216,512) (k dead)
    attn_kernel<<<dim3(36, 64), 256, 0, stream>>>(q_bf, ksel, vsel, attn_t);
    // 11. out_pre = w_out @ attn -> fp32 d_out
    gemm_mfma<<<dim3(72, 2, 8), 256, 0, stream>>>(
        wo_h, attn_t, out, 256, 9216, 512, 9216LL * 512, 256LL * 9216);
    // 12. final chan_norm + gamma*out + residual, in-place on d_out
    final_kernel<<<288, 256, 0, stream>>>(out_g, out_b, gamma, qsrc, out);
}

// Round 5
// 776.422 us; speedup vs baseline: 2.8186x; 1.1954x over previous
//
#include <hip/hip_runtime.h>
#include <math.h>

// DPCA2D: dual-pruned cosine-sim cross-attention.
// B=8, C=256, Nq=9216 (96x96), Nc=4096 (64x64), INNER=512, HEADS=8, D=64,
// BH=64, top-k 8x8 -> 64 kept tokens.
//
// Round 5: attention -> MFMA flash-style (sim MFMA -> exp/denom -> P via LDS
// -> PV MFMA). q stored (bh,p,64) p-major by the q-GEMM epilogue; K [t][d] and
// V^T [d][t] in bf16. Selection path (fp32 k, exact norms/probe) unchanged.

#define EPSN 1e-5f

typedef __attribute__((ext_vector_type(8))) short bf16x8;
typedef __attribute__((ext_vector_type(4))) float f32x4;

__device__ inline unsigned short f2bf(float f) {
    unsigned u = __float_as_uint(f);
    u += 0x7fff + ((u >> 16) & 1);          // RNE
    return (unsigned short)(u >> 16);
}
__device__ inline float bf2f(unsigned short h) {
    return __uint_as_float((unsigned)h << 16);
}

#define GL2LDS(g, s) __builtin_amdgcn_global_load_lds( \
    (const __attribute__((address_space(1))) void*)(g), \
    (__attribute__((address_space(3))) void*)(s), 16, 0, 0)

// ---------------- fp32 -> bf16 hi/lo split (weights) ----------------
__global__ __launch_bounds__(256) void cvt_split_kernel(
    const float* __restrict__ x, unsigned short* __restrict__ hi,
    unsigned short* __restrict__ lo, int n)
{
    int i = blockIdx.x * 256 + threadIdx.x;
    if (i < n) {
        float v = x[i];
        unsigned short h = f2bf(v);
        hi[i] = h;
        lo[i] = f2bf(v - bf2f(h));
    }
}
__global__ __launch_bounds__(256) void cvt_bf16_kernel(
    const float* __restrict__ x, unsigned short* __restrict__ y, int n)
{
    int i = blockIdx.x * 256 + threadIdx.x;
    if (i < n) y[i] = f2bf(x[i]);
}

// ---------------- channel LayerNorm -> transposed bf16 hi/lo ------------
__global__ __launch_bounds__(256) void chan_norm_split_kernel(
    const float* __restrict__ x, const float* __restrict__ g,
    const float* __restrict__ bb, unsigned short* __restrict__ yh,
    unsigned short* __restrict__ yl, int N)
{
    int idx = blockIdx.x * 256 + threadIdx.x;
    int b = idx / N, p = idx - b * N;
    const float* xb = x + (size_t)b * 256 * N + p;
    float mean = 0.f, m2 = 0.f;
    for (int c = 0; c < 256; ++c) {
        float v = xb[(size_t)c * N];
        mean += v; m2 += v * v;
    }
    mean *= (1.f / 256.f); m2 *= (1.f / 256.f);
    float inv = 1.f / sqrtf(m2 - mean * mean + EPSN);
    uint4* yhr = (uint4*)(yh + ((size_t)b * N + p) * 256);
    uint4* ylr = (uint4*)(yl + ((size_t)b * N + p) * 256);
    for (int c0 = 0; c0 < 256; c0 += 8) {
        unsigned short hh[8], ll[8];
        #pragma unroll
        for (int j = 0; j < 8; ++j) {
            int c = c0 + j;
            float v = (xb[(size_t)c * N] - mean) * inv * g[c] + bb[c];
            hh[j] = f2bf(v);
            ll[j] = f2bf(v - bf2f(hh[j]));
        }
        uint4 ph, pl;
        ph.x = (unsigned)hh[0] | ((unsigned)hh[1] << 16);
        ph.y = (unsigned)hh[2] | ((unsigned)hh[3] << 16);
        ph.z = (unsigned)hh[4] | ((unsigned)hh[5] << 16);
        ph.w = (unsigned)hh[6] | ((unsigned)hh[7] << 16);
        pl.x = (unsigned)ll[0] | ((unsigned)ll[1] << 16);
        pl.y = (unsigned)ll[2] | ((unsigned)ll[3] << 16);
        pl.z = (unsigned)ll[4] | ((unsigned)ll[5] << 16);
        pl.w = (unsigned)ll[6] | ((unsigned)ll[7] << 16);
        yhr[c0 >> 3] = ph;
        ylr[c0 >> 3] = pl;
    }
}

// ---------------- split-bf16 MFMA GEMM: C = A @ Bt^T (x3 passes) ---------
// MODE 0: fp32 C (z,M,N). MODE 1: q epilogue — exact col norms + qprobe from
// fp32 acc; store pre-normalized q bf16 in (bh, p, 64) p-major layout.
template <int MODE>
__global__ __launch_bounds__(256) void gemm_x3(
    const unsigned short* __restrict__ Ah, const unsigned short* __restrict__ Al,
    const unsigned short* __restrict__ Bth, const unsigned short* __restrict__ Btl,
    void* __restrict__ Cv, float* __restrict__ qprobe,
    int M, int N, int K, long long strideBt, long long strideC)
{
    __shared__ unsigned short AsH[128 * 32], AsL[128 * 32];
    __shared__ unsigned short BsH[128 * 32], BsL[128 * 32];
    const unsigned short* BzH = Bth + (size_t)blockIdx.z * strideBt;
    const unsigned short* BzL = Btl + (size_t)blockIdx.z * strideBt;
    int n0 = blockIdx.x * 128, m0 = blockIdx.y * 128;
    int t = threadIdx.x;
    int w = t >> 6, l = t & 63;
    int wm = (w >> 1) * 64, wn = (w & 1) * 64;
    int lc = l & 15, quad = l >> 4;

    f32x4 acc[4][4];
    #pragma unroll
    for (int i = 0; i < 4; ++i)
        #pragma unroll
        for (int j = 0; j < 4; ++j) acc[i][j] = {0.f, 0.f, 0.f, 0.f};

    int srow = t >> 2;
    int sseg = (t & 3) * 8;
    for (int k0 = 0; k0 < K; k0 += 32) {
        size_t a0 = (size_t)(m0 + srow) * K + k0 + sseg;
        size_t a1 = (size_t)(m0 + 64 + srow) * K + k0 + sseg;
        size_t b0 = (size_t)(n0 + srow) * K + k0 + sseg;
        size_t b1 = (size_t)(n0 + 64 + srow) * K + k0 + sseg;
        __syncthreads();
        GL2LDS(Ah + a0, AsH + (size_t)t * 8);
        GL2LDS(Ah + a1, AsH + 2048 + (size_t)t * 8);
        GL2LDS(Al + a0, AsL + (size_t)t * 8);
        GL2LDS(Al + a1, AsL + 2048 + (size_t)t * 8);
        GL2LDS(BzH + b0, BsH + (size_t)t * 8);
        GL2LDS(BzH + b1, BsH + 2048 + (size_t)t * 8);
        GL2LDS(BzL + b0, BsL + (size_t)t * 8);
        GL2LDS(BzL + b1, BsL + 2048 + (size_t)t * 8);
        __syncthreads();
        bf16x8 ah[4], al_[4], bh_[4], bl_[4];
        #pragma unroll
        for (int i = 0; i < 4; ++i) {
            ah[i]  = *(const bf16x8*)(AsH + (size_t)(wm + i * 16 + lc) * 32 + quad * 8);
            al_[i] = *(const bf16x8*)(AsL + (size_t)(wm + i * 16 + lc) * 32 + quad * 8);
        }
        #pragma unroll
        for (int j = 0; j < 4; ++j) {
            bh_[j] = *(const bf16x8*)(BsH + (size_t)(wn + j * 16 + lc) * 32 + quad * 8);
            bl_[j] = *(const bf16x8*)(BsL + (size_t)(wn + j * 16 + lc) * 32 + quad * 8);
        }
        #pragma unroll
        for (int i = 0; i < 4; ++i)
            #pragma unroll
            for (int j = 0; j < 4; ++j) {
                acc[i][j] = __builtin_amdgcn_mfma_f32_16x16x32_bf16(al_[i], bh_[j], acc[i][j], 0, 0, 0);
                acc[i][j] = __builtin_amdgcn_mfma_f32_16x16x32_bf16(ah[i],  bl_[j], acc[i][j], 0, 0, 0);
                acc[i][j] = __builtin_amdgcn_mfma_f32_16x16x32_bf16(ah[i],  bh_[j], acc[i][j], 0, 0, 0);
            }
    }
    // C/D layout: col=lane&15, row=quad*4+reg (m89-verified)
    if (MODE == 0) {
        float* C = (float*)Cv;
        size_t cbase = (size_t)blockIdx.z * strideC;
        #pragma unroll
        for (int i = 0; i < 4; ++i)
            #pragma unroll
            for (int j = 0; j < 4; ++j)
                #pragma unroll
                for (int r = 0; r < 4; ++r) {
                    int row = m0 + wm + i * 16 + quad * 4 + r;
                    int col = n0 + wn + j * 16 + lc;
                    C[cbase + (size_t)row * N + col] = acc[i][j][r];
                }
    } else {
        // wave's 64 M-rows = one head: exact column norms in-wave
        float inv[4];
        #pragma unroll
        for (int j = 0; j < 4; ++j) {
            float s = 0.f;
            #pragma unroll
            for (int i = 0; i < 4; ++i)
                #pragma unroll
                for (int r = 0; r < 4; ++r) s += acc[i][j][r] * acc[i][j][r];
            s += __shfl_xor(s, 16);
            s += __shfl_xor(s, 32);
            inv[j] = 1.f / fmaxf(sqrtf(s), 1e-12f);
        }
        // store q_n bf16, layout (bh, p, 64): 4 consecutive d per 8B store
        unsigned short* qbf = (unsigned short*)Cv;
        #pragma unroll
        for (int i = 0; i < 4; ++i) {
            int row0 = m0 + wm + i * 16 + quad * 4;
            int h = row0 >> 6, d0 = row0 & 63;
            #pragma unroll
            for (int j = 0; j < 4; ++j) {
                int col = n0 + wn + j * 16 + lc;
                size_t addr = ((size_t)(blockIdx.z * 8 + h) * 9216 + col) * 64 + d0;
                unsigned lo = (unsigned)f2bf(acc[i][j][0] * inv[j])
                            | ((unsigned)f2bf(acc[i][j][1] * inv[j]) << 16);
                unsigned hi = (unsigned)f2bf(acc[i][j][2] * inv[j])
                            | ((unsigned)f2bf(acc[i][j][3] * inv[j]) << 16);
                uint2 pk; pk.x = lo; pk.y = hi;
                *(uint2*)(qbf + addr) = pk;
            }
        }
        int bh = blockIdx.z * 8 + ((m0 + wm) >> 6);
        #pragma unroll
        for (int i = 0; i < 4; ++i)
            #pragma unroll
            for (int r = 0; r < 4; ++r) {
                float s = 0.f;
                #pragma unroll
                for (int j = 0; j < 4; ++j) s += acc[i][j][r] * inv[j];
                s += __shfl_xor(s, 1);
                s += __shfl_xor(s, 2);
                s += __shfl_xor(s, 4);
                s += __shfl_xor(s, 8);
                if (lc == 0)
                    atomicAdd(&qprobe[bh * 64 + i * 16 + quad * 4 + r], s);
            }
    }
}

// ---------------- plain bf16 MFMA GEMM (out projection) ------------------
__global__ __launch_bounds__(256) void gemm_mfma(
    const unsigned short* __restrict__ A, const unsigned short* __restrict__ Bt,
    float* __restrict__ C, int M, int N, int K,
    long long strideBt, long long strideC)
{
    __shared__ unsigned short As[128 * 32];
    __shared__ unsigned short Bs[128 * 32];
    const unsigned short* Bz = Bt + (size_t)blockIdx.z * strideBt;
    int n0 = blockIdx.x * 128, m0 = blockIdx.y * 128;
    int t = threadIdx.x;
    int w = t >> 6, l = t & 63;
    int wm = (w >> 1) * 64, wn = (w & 1) * 64;
    int lc = l & 15, quad = l >> 4;
    f32x4 acc[4][4];
    #pragma unroll
    for (int i = 0; i < 4; ++i)
        #pragma unroll
        for (int j = 0; j < 4; ++j) acc[i][j] = {0.f, 0.f, 0.f, 0.f};
    int srow = t >> 2, sseg = (t & 3) * 8;
    for (int k0 = 0; k0 < K; k0 += 32) {
        const unsigned short* ga0 = A  + (size_t)(m0 + srow)      * K + k0 + sseg;
        const unsigned short* ga1 = A  + (size_t)(m0 + 64 + srow) * K + k0 + sseg;
        const unsigned short* gb0 = Bz + (size_t)(n0 + srow)      * K + k0 + sseg;
        const unsigned short* gb1 = Bz + (size_t)(n0 + 64 + srow) * K + k0 + sseg;
        __syncthreads();
        GL2LDS(ga0, As + (size_t)t * 8);
        GL2LDS(ga1, As + 2048 + (size_t)t * 8);
        GL2LDS(gb0, Bs + (size_t)t * 8);
        GL2LDS(gb1, Bs + 2048 + (size_t)t * 8);
        __syncthreads();
        bf16x8 af[4], bfr[4];
        #pragma unroll
        for (int i = 0; i < 4; ++i)
            af[i] = *(const bf16x8*)(As + (size_t)(wm + i * 16 + lc) * 32 + quad * 8);
        #pragma unroll
        for (int j = 0; j < 4; ++j)
            bfr[j] = *(const bf16x8*)(Bs + (size_t)(wn + j * 16 + lc) * 32 + quad * 8);
        #pragma unroll
        for (int i = 0; i < 4; ++i)
            #pragma unroll
            for (int j = 0; j < 4; ++j)
                acc[i][j] = __builtin_amdgcn_mfma_f32_16x16x32_bf16(af[i], bfr[j], acc[i][j], 0, 0, 0);
    }
    size_t cbase = (size_t)blockIdx.z * strideC;
    #pragma unroll
    for (int i = 0; i < 4; ++i)
        #pragma unroll
        for (int j = 0; j < 4; ++j)
            #pragma unroll
            for (int r = 0; r < 4; ++r) {
                int row = m0 + wm + i * 16 + quad * 4 + r;
                int col = n0 + wn + j * 16 + lc;
                C[cbase + (size_t)row * N + col] = acc[i][j][r];
            }
}

// ---------------- l2 inverse norm (fp32 k) ----------------
__global__ __launch_bounds__(256) void l2inv_f32_kernel(
    const float* __restrict__ x, float* __restrict__ inv, int N,
    long long strideB, long long strideH)
{
    int idx = blockIdx.x * 256 + threadIdx.x;
    int bh = idx / N, p = idx - bh * N;
    const float* base = x + (size_t)(bh >> 3) * strideB + (size_t)(bh & 7) * strideH + p;
    float ss = 0.f;
    #pragma unroll 8
    for (int d = 0; d < 64; ++d) { float v = base[(size_t)d * N]; ss += v * v; }
    inv[idx] = 1.f / fmaxf(sqrtf(ss), 1e-12f);
}

// ---------------- row/col sums of |k_n| per bh ---------------------------
__global__ __launch_bounds__(256) void krowcol_kernel(
    const float* __restrict__ k, const float* __restrict__ invnk,
    float* __restrict__ krow, float* __restrict__ kcol)
{
    int bh = blockIdx.x, b = bh >> 3, h = bh & 7;
    int d0 = blockIdx.y * 8;
    const float* kbase = k + ((size_t)b * 512 + (size_t)h * 64) * 4096;
    __shared__ float inv_s[4096];
    __shared__ float tile[64 * 65];
    int t = threadIdx.x;
    for (int l = t; l < 4096; l += 256) inv_s[l] = invnk[(size_t)bh * 4096 + l];
    for (int dd = 0; dd < 8; ++dd) {
        int d = d0 + dd;
        __syncthreads();
        for (int l = t; l < 4096; l += 256)
            tile[(l >> 6) * 65 + (l & 63)] = kbase[(size_t)d * 4096 + l];
        __syncthreads();
        if (t < 64) {
            float s = 0.f;
            for (int ww = 0; ww < 64; ++ww) s += fabsf(tile[t * 65 + ww]) * inv_s[t * 64 + ww];
            krow[((size_t)bh * 64 + d) * 64 + t] = s;
        } else if (t < 128) {
            int ww = t - 64;
            float s = 0.f;
            for (int hh = 0; hh < 64; ++hh) s += fabsf(tile[hh * 65 + ww]) * inv_s[hh * 64 + ww];
            kcol[((size_t)bh * 64 + d) * 64 + ww] = s;
        }
    }
}

// ---------------- top-8 row/col selection per bh -------------------------
__global__ void topk_kernel(const float* __restrict__ qprobe,
                            const float* __restrict__ krow,
                            const float* __restrict__ kcol,
                            int* __restrict__ toph, int* __restrict__ topw)
{
    int bh = blockIdx.x, t = threadIdx.x;  // 64 threads
    __shared__ float qp[64], sr[64], sc[64];
    qp[t] = qprobe[bh * 64 + t];
    __syncthreads();
    float s1 = 0.f, s2 = 0.f;
    for (int d = 0; d < 64; ++d) {
        float qv = qp[d];
        s1 += qv * krow[((size_t)bh * 64 + d) * 64 + t];
        s2 += qv * kcol[((size_t)bh * 64 + d) * 64 + t];
    }
    sr[t] = s1; sc[t] = s2;
    __syncthreads();
    if (t == 0) {
        unsigned long long used = 0ull;
        for (int it = 0; it < 8; ++it) {
            int best = -1; float bv = -INFINITY;
            for (int i = 0; i < 64; ++i)
                if (!((used >> i) & 1ull) && sr[i] > bv) { bv = sr[i]; best = i; }
            if (best < 0) best = it;
            used |= 1ull << best;
            toph[bh * 8 + it] = best;
        }
        used = 0ull;
        for (int it = 0; it < 8; ++it) {
            int best = -1; float bv = -INFINITY;
            for (int i = 0; i < 64; ++i)
                if (!((used >> i) & 1ull) && sc[i] > bv) { bv = sc[i]; best = i; }
            if (best < 0) best = it;
            used |= 1ull << best;
            topw[bh * 8 + it] = best;
        }
    }
}

// ---------------- gather pruned normalized K -> bf16 [bh][t][d] ----------
__global__ __launch_bounds__(256) void gather_k_kernel(
    const float* __restrict__ k, const float* __restrict__ invnk,
    const int* __restrict__ toph, const int* __restrict__ topw,
    unsigned short* __restrict__ ksel)
{
    int bh = blockIdx.x, b = bh >> 3, h = bh & 7;
    __shared__ int th_s[8], tw_s[8];
    if (threadIdx.x < 8) th_s[threadIdx.x] = toph[bh * 8 + threadIdx.x];
    else if (threadIdx.x < 16) tw_s[threadIdx.x - 8] = topw[bh * 8 + threadIdx.x - 8];
    __syncthreads();
    const float* kbase = k + ((size_t)b * 512 + (size_t)h * 64) * 4096;
    for (int l = threadIdx.x; l < 4096; l += 256) {
        int tok = l >> 6, d = l & 63;
        int p = th_s[tok >> 3] * 64 + tw_s[tok & 7];
        ksel[(size_t)bh * 4096 + l] = f2bf(kbase[(size_t)d * 4096 + p] * invnk[(size_t)bh * 4096 + p]);
    }
}

// ---------------- V at gathered positions -> bf16 transposed [bh][d][t] --
__global__ __launch_bounds__(256) void vsel_kernel(
    const float* __restrict__ w_kv, const unsigned short* __restrict__ ctxt,
    const int* __restrict__ toph, const int* __restrict__ topw,
    unsigned short* __restrict__ vt)
{
    int bh = blockIdx.x, b = bh >> 3, h = bh & 7;
    __shared__ int th_s[8], tw_s[8];
    if (threadIdx.x < 8) th_s[threadIdx.x] = toph[bh * 8 + threadIdx.x];
    else if (threadIdx.x < 16) tw_s[threadIdx.x - 8] = topw[bh * 8 + threadIdx.x - 8];
    __syncthreads();
    const unsigned short* cb = ctxt + (size_t)b * 4096 * 256;
    int l = blockIdx.y * 1024 + threadIdx.x;
    for (int it = 0; it < 4; ++it, l += 256) {
        int tok = l >> 6, d = l & 63;
        int p = th_s[tok >> 3] * 64 + tw_s[tok & 7];
        const float* wr = w_kv + (size_t)(512 + h * 64 + d) * 256;
        const unsigned short* cr = cb + (size_t)p * 256;
        float s = 0.f;
        for (int c = 0; c < 256; ++c) s += wr[c] * bf2f(cr[c]);
        vt[(size_t)bh * 4096 + d * 64 + tok] = f2bf(s);
    }
}

// ---------------- MFMA flash-style attention ------------------------------
// q_pd: (bh, 9216, 64) bf16 pre-normalized. ksel: (bh,64t,64d). vt: (bh,64d,64t).
// attn_t: (b, 9216, 512) bf16. Block = 4 waves x 16 p = 64 p, grid (144, 64).
// Fixed softmax shift 1.0 (unit q,k -> sim <= 1).
#define LPAD 72
__global__ __launch_bounds__(256) void attn_mfma_kernel(
    const unsigned short* __restrict__ q_pd, const unsigned short* __restrict__ ksel,
    const unsigned short* __restrict__ vt, unsigned short* __restrict__ attn_t)
{
    int bh = blockIdx.y, b = bh >> 3, h = bh & 7;
    __shared__ unsigned short Ks[64 * LPAD];      // [t][d]
    __shared__ unsigned short Vs[64 * LPAD];      // [d][t]
    __shared__ unsigned short Ps[4][16 * LPAD];   // per-wave [p][t]
    int t = threadIdx.x, w = t >> 6, l = t & 63;
    int lc = l & 15, quad = l >> 4;
    // stage K,V (padded rows, 16B chunks): 512 chunks over 256 threads x2
    {
        int r0 = t >> 3, c0 = (t & 7) * 8;        // rows 0..31
        const unsigned short* kg = ksel + (size_t)bh * 4096;
        const unsigned short* vg = vt + (size_t)bh * 4096;
        *(uint4*)(Ks + r0 * LPAD + c0)        = *(const uint4*)(kg + r0 * 64 + c0);
        *(uint4*)(Ks + (r0 + 32) * LPAD + c0) = *(const uint4*)(kg + (r0 + 32) * 64 + c0);
        *(uint4*)(Vs + r0 * LPAD + c0)        = *(const uint4*)(vg + r0 * 64 + c0);
        *(uint4*)(Vs + (r0 + 32) * LPAD + c0) = *(const uint4*)(vg + (r0 + 32) * 64 + c0);
    }
    __syncthreads();
    int p0 = blockIdx.x * 64 + w * 16;
    // Q fragments: A[m=p][k=d] contiguous from (bh,p,64)
    const unsigned short* qrow = q_pd + ((size_t)bh * 9216 + p0 + lc) * 64;
    bf16x8 aq0 = *(const bf16x8*)(qrow + quad * 8);
    bf16x8 aq1 = *(const bf16x8*)(qrow + 32 + quad * 8);
    // sim = Q K^T  (M=p, N=t, K=d)
    f32x4 sacc[4];
    #pragma unroll
    for (int j = 0; j < 4; ++j) sacc[j] = {0.f, 0.f, 0.f, 0.f};
    #pragma unroll
    for (int j = 0; j < 4; ++j) {
        bf16x8 bk0 = *(const bf16x8*)(Ks + (j * 16 + lc) * LPAD + quad * 8);
        bf16x8 bk1 = *(const bf16x8*)(Ks + (j * 16 + lc) * LPAD + 32 + quad * 8);
        sacc[j] = __builtin_amdgcn_mfma_f32_16x16x32_bf16(aq0, bk0, sacc[j], 0, 0, 0);
        sacc[j] = __builtin_amdgcn_mfma_f32_16x16x32_bf16(aq1, bk1, sacc[j], 0, 0, 0);
    }
    // exp + per-row denom (row p = quad*4+r, col t = j*16+lc)
    float e[4][4], den[4] = {0.f, 0.f, 0.f, 0.f};
    #pragma unroll
    for (int j = 0; j < 4; ++j)
        #pragma unroll
        for (int r = 0; r < 4; ++r) {
            float v = __expf(sacc[j][r] - 1.f);
            e[j][r] = v; den[r] += v;
        }
    #pragma unroll
    for (int r = 0; r < 4; ++r) {
        den[r] += __shfl_xor(den[r], 1);
        den[r] += __shfl_xor(den[r], 2);
        den[r] += __shfl_xor(den[r], 4);
        den[r] += __shfl_xor(den[r], 8);
    }
    // P (C-layout) -> LDS -> A-layout
    #pragma unroll
    for (int j = 0; j < 4; ++j)
        #pragma unroll
        for (int r = 0; r < 4; ++r)
            Ps[w][(quad * 4 + r) * LPAD + j * 16 + lc] = f2bf(e[j][r]);
    __syncthreads();
    bf16x8 ap0 = *(const bf16x8*)(Ps[w] + lc * LPAD + quad * 8);
    bf16x8 ap1 = *(const bf16x8*)(Ps[w] + lc * LPAD + 32 + quad * 8);
    // O = P V  (M=p, N=d, K=t)
    f32x4 oacc[4];
    #pragma unroll
    for (int j = 0; j < 4; ++j) oacc[j] = {0.f, 0.f, 0.f, 0.f};
    #pragma unroll
    for (int j = 0; j < 4; ++j) {
        bf16x8 bv0 = *(const bf16x8*)(Vs + (j * 16 + lc) * LPAD + quad * 8);
        bf16x8 bv1 = *(const bf16x8*)(Vs + (j * 16 + lc) * LPAD + 32 + quad * 8);
        oacc[j] = __builtin_amdgcn_mfma_f32_16x16x32_bf16(ap0, bv0, oacc[j], 0, 0, 0);
        oacc[j] = __builtin_amdgcn_mfma_f32_16x16x32_bf16(ap1, bv1, oacc[j], 0, 0, 0);
    }
    float rd[4];
    #pragma unroll
    for (int r = 0; r < 4; ++r) rd[r] = 1.f / den[r];
    // store: row p = quad*4+r (same quad/r as den), col d = j*16+lc
    #pragma unroll
    for (int j = 0; j < 4; ++j)
        #pragma unroll
        for (int r = 0; r < 4; ++r) {
            int p = p0 + quad * 4 + r;
            int d = j * 16 + lc;
            attn_t[((size_t)b * 9216 + p) * 512 + h * 64 + d] = f2bf(oacc[j][r] * rd[r]);
        }
}

// ---------------- final: chan_norm + gamma*out + residual (in-place) -----
__global__ __launch_bounds__(256) void final_kernel(
    const float* __restrict__ g, const float* __restrict__ bb,
    const float* __restrict__ gamma, const float* __restrict__ qsrc,
    float* __restrict__ out)
{
    int idx = blockIdx.x * 256 + threadIdx.x;  // b*9216 + p
    int b = idx / 9216, p = idx - b * 9216;
    float* xb = out + (size_t)b * 256 * 9216 + p;
    float mean = 0.f, m2 = 0.f;
    for (int c = 0; c < 256; ++c) {
        float v = xb[(size_t)c * 9216];
        mean += v; m2 += v * v;
    }
    mean *= (1.f / 256.f); m2 *= (1.f / 256.f);
    float inv = 1.f / sqrtf(m2 - mean * mean + EPSN);
    float gm = gamma[0];
    const float* qs = qsrc + (size_t)b * 256 * 9216 + p;
    for (int c = 0; c < 256; ++c) {
        float v = (xb[(size_t)c * 9216] - mean) * inv * g[c] + bb[c];
        xb[(size_t)c * 9216] = gm * v + qs[(size_t)c * 9216];
    }
}

extern "C" void kernel_launch(void* const* d_in, const int* in_sizes, int n_in,
                              void* d_out, int out_size, void* d_ws, size_t ws_size,
                              hipStream_t stream) {
    const float* qsrc  = (const float*)d_in[0];
    const float* ctx   = (const float*)d_in[1];
    const float* qs_g  = (const float*)d_in[2];
    const float* qs_b  = (const float*)d_in[3];
    const float* ctx_g = (const float*)d_in[4];
    const float* ctx_b = (const float*)d_in[5];
    const float* out_g = (const float*)d_in[6];
    const float* out_b = (const float*)d_in[7];
    const float* w_q   = (const float*)d_in[8];
    const float* w_kv  = (const float*)d_in[9];
    const float* w_out = (const float*)d_in[10];
    const float* gamma = (const float*)d_in[11];
    float* out = (float*)d_out;

    // ---- workspace (bytes), peak ~190 MB, liveness-aliased ----
    // Region A @0 (75,497,472): qs_h+qs_l [1-2]; k_f fp32 [4-8]; attn_t [10-11]
    // Region B @75,497,472 (75,497,472): q_pd bf16 (bh,9216,64) [2-10]
    // Region C @150,994,944 (33,554,432): ctx_h+ctx_l [3-9]
    char* base = (char*)d_ws;
    unsigned short* qs_h  = (unsigned short*)(base + 0);
    unsigned short* qs_l  = (unsigned short*)(base + 37748736);
    float*          k_f   = (float*)        (base + 0);
    unsigned short* attn_t= (unsigned short*)(base + 0);
    unsigned short* q_pd  = (unsigned short*)(base + 75497472);
    unsigned short* ctx_h = (unsigned short*)(base + 150994944);
    unsigned short* ctx_l = (unsigned short*)(base + 167772160);
    char* S = base + 184549376;
    float* invnk = (float*)S;                     S += 262144 * 4;
    float* krow  = (float*)S;                     S += 262144 * 4;
    float* kcol  = (float*)S;                     S += 262144 * 4;
    float* qprob = (float*)S;                     S += 4096 * 4;
    unsigned short* ksel = (unsigned short*)S;    S += 262144 * 2;
    unsigned short* vt   = (unsigned short*)S;    S += 262144 * 2;
    int*   toph  = (int*)S;                       S += 512 * 4;
    int*   topw  = (int*)S;                       S += 512 * 4;
    unsigned short* wq_h = (unsigned short*)S;    S += 131072 * 2;
    unsigned short* wq_l = (unsigned short*)S;    S += 131072 * 2;
    unsigned short* wk_h = (unsigned short*)S;    S += 131072 * 2;
    unsigned short* wk_l = (unsigned short*)S;    S += 131072 * 2;
    unsigned short* wo_h = (unsigned short*)S;    S += 131072 * 2;

    // 0. weight splits
    cvt_split_kernel<<<512, 256, 0, stream>>>(w_q, wq_h, wq_l, 131072);
    cvt_split_kernel<<<512, 256, 0, stream>>>(w_kv, wk_h, wk_l, 131072);
    cvt_bf16_kernel<<<512, 256, 0, stream>>>(w_out, wo_h, 131072);
    hipMemsetAsync(qprob, 0, 4096 * sizeof(float), stream);
    // 1. qs hi/lo = chan_norm(query_source)^T
    chan_norm_split_kernel<<<288, 256, 0, stream>>>(qsrc, qs_g, qs_b, qs_h, qs_l, 9216);
    // 2. q = w_q @ qs (bf16x3) -> q_pd (bh,p,64) + qprobe (fused epilogue)
    gemm_x3<1><<<dim3(72, 4, 8), 256, 0, stream>>>(
        wq_h, wq_l, qs_h, qs_l, q_pd, qprob, 512, 9216, 256,
        9216LL * 256, 0);
    // 3. ctx hi/lo = chan_norm(context)^T
    chan_norm_split_kernel<<<128, 256, 0, stream>>>(ctx, ctx_g, ctx_b, ctx_h, ctx_l, 4096);
    // 4. k = w_kv[0:512] @ ctx (bf16x3) -> fp32 (qs region dead)
    gemm_x3<0><<<dim3(32, 4, 8), 256, 0, stream>>>(
        wk_h, wk_l, ctx_h, ctx_l, k_f, nullptr, 512, 4096, 256,
        4096LL * 256, 512LL * 4096);
    // 5. inverse l2 norms of k
    l2inv_f32_kernel<<<1024, 256, 0, stream>>>(k_f, invnk, 4096, 512LL * 4096, 64LL * 4096);
    // 6. |k_n| row/col marginals
    krowcol_kernel<<<dim3(64, 8), 256, 0, stream>>>(k_f, invnk, krow, kcol);
    // 7. top-8 rows/cols
    topk_kernel<<<64, 64, 0, stream>>>(qprob, krow, kcol, toph, topw);
    // 8. gather pruned normalized K -> bf16 [t][d]
    gather_k_kernel<<<64, 256, 0, stream>>>(k_f, invnk, toph, topw, ksel);
    // 9. V at gathered positions -> bf16 [d][t]
    vsel_kernel<<<dim3(64, 4), 256, 0, stream>>>(w_kv, ctx_h, toph, topw, vt);
    // 10. MFMA attention -> attn_t bf16 (b,9216,512) (k dead)
    attn_mfma_kernel<<<dim3(144, 64), 256, 0, stream>>>(q_pd, ksel, vt, attn_t);
    // 11. out_pre = w_out @ attn -> fp32 d_out
    gemm_mfma<<<dim3(72, 2, 8), 256, 0, stream>>>(
        wo_h, attn_t, out, 256, 9216, 512, 9216LL * 512, 256LL * 9216);
    // 12. final chan_norm + gamma*out + residual, in-place on d_out
    final_kernel<<<288, 256, 0, stream>>>(out_g, out_b, gamma, qsrc, out);
}